// Round 1
// baseline (1532.856 us; speedup 1.0000x reference)
//
#include <hip/hip_runtime.h>
#include <hip/hip_fp16.h>
#include <math.h>

#define NANG 9
#define SS 16
#define NPIX 256
#define WSTRIDE 70
#define FLTMAX_BITS 0x7F7FFFFFu

// Per-(angle,pixel) bilinear table entry, 16B:
//  wx = packed half2 (ewx0, ewx1)  -- x-weights with block-validity folded in
//  wy = packed half2 (ewy0, ewy1)
//  mn = m[p] / msum[angle]         -- mask * normalization, fp32
//  xy = (x0+1) | ((y0+1)<<8)       -- top-left tap, biased so >=0
struct __align__(16) TEntry { unsigned wx, wy; float mn; unsigned xy; };

__global__ __launch_bounds__(256) void build_table(TEntry* __restrict__ tbl)
{
    __shared__ float red[256];
    const int p  = threadIdx.x;
    const int px = p & 15, py = p >> 4;
    for (int a = 0; a < NANG; ++a) {
        double t  = (double)(a - 4) * 0.017453292519943295; // deg2rad
        double ca = cos(t), sa = sin(t);
        // matches numpy float64 math then cast to f32 (reference _rot_grid)
        float sx = (float)(ca * px - sa * py + (1.0 - ca) * 8.0 + sa * 8.0);
        float sy = (float)(sa * px + ca * py - sa * 8.0 + (1.0 - ca) * 8.0);
        float x0f = floorf(sx), y0f = floorf(sy);
        int   x0  = (int)x0f,   y0  = (int)y0f;
        float wx1 = sx - x0f, wx0 = 1.0f - wx1;
        float wy1 = sy - y0f, wy0 = 1.0f - wy1;
        float ewx0 = (x0 >= 0 && x0 < SS)         ? wx0 : 0.0f;
        float ewx1 = (x0 + 1 >= 0 && x0 + 1 < SS) ? wx1 : 0.0f;
        float ewy0 = (y0 >= 0 && y0 < SS)         ? wy0 : 0.0f;
        float ewy1 = (y0 + 1 >= 0 && y0 + 1 < SS) ? wy1 : 0.0f;
        float m = (ewx0 + ewx1) * (ewy0 + ewy1);

        red[p] = m;
        __syncthreads();
        for (int s = 128; s > 0; s >>= 1) {
            if (p < s) red[p] += red[p + s];
            __syncthreads();
        }
        float msum = red[0];
        __syncthreads();

        x0 = max(-1, min(15, x0));   // LDS bounds safety (weights already handle validity)
        y0 = max(-1, min(15, y0));
        TEntry e;
        e.wx = (unsigned)__half_as_ushort(__float2half(ewx0)) |
               ((unsigned)__half_as_ushort(__float2half(ewx1)) << 16);
        e.wy = (unsigned)__half_as_ushort(__float2half(ewy0)) |
               ((unsigned)__half_as_ushort(__float2half(ewy1)) << 16);
        e.mn = m / msum;
        e.xy = (unsigned)(x0 + 1) | ((unsigned)(y0 + 1) << 8);
        tbl[a * NPIX + p] = e;
    }
}

// One block per batch image. LDS: zero-padded 70x70 fm2 window (covers all
// subblock/shift/tap accesses exactly), full 9x256 bilinear table, 16 submins.
// Work item = (angle, subblock, by-shift); each item keeps 9 bx-shift
// accumulators so one 2x10-value LDS row read serves 9 candidates.
__global__ __launch_bounds__(256) void randip_main(const float* __restrict__ fm1,
                                                   const float* __restrict__ fm2,
                                                   const TEntry* __restrict__ gtbl,
                                                   float* __restrict__ out)
{
    __shared__ float  win[WSTRIDE * WSTRIDE];   // 19600 B
    __shared__ TEntry tbl[NANG * NPIX];         // 36864 B
    __shared__ unsigned submin[16];

    const int b   = blockIdx.x;
    const int tid = threadIdx.x;

    for (int i = tid; i < WSTRIDE * WSTRIDE; i += 256) win[i] = 0.0f;
    {
        const uint4* src = (const uint4*)gtbl;
        uint4*       dst = (uint4*)tbl;
        for (int i = tid; i < NANG * NPIX; i += 256) dst[i] = src[i];
    }
    if (tid < 16) submin[tid] = FLTMAX_BITS;
    __syncthreads();

    const float* img2 = fm2 + (size_t)b * 4096;
    for (int i = tid; i < 4096; i += 256) {
        int y = i >> 6, x = i & 63;
        win[(y + 1) * WSTRIDE + (x + 1)] = img2[i];
    }
    __syncthreads();

    const float* img1 = fm1 + (size_t)b * 4096;

    // item = ((a*16 + sub)*9 + by): by fastest across lanes -> win rows spread
    // across banks; angle mostly uniform per wave -> table reads broadcast.
    for (int item = tid; item < NANG * 16 * 9; item += 256) {
        const int by   = item % 9;
        const int rest = item / 9;
        const int sub  = rest & 15;
        const int a    = rest >> 4;
        const int sub_x = (sub & 3) << 4;
        const int sub_y = (sub >> 2) << 4;
        const int x_lo = max(sub_x - 4, 0);
        const int x_hi = min(sub_x + 4, 48);
        const int y_lo = max(sub_y - 4, 0);
        const int y_hi = min(sub_y + 4, 48);
        const bool by_valid = (y_lo + by) <= y_hi;
        const int  nvx = x_hi - x_lo;           // valid bx: 0..nvx

        float acc[9];
        #pragma unroll
        for (int j = 0; j < 9; ++j) acc[j] = 0.0f;

        const TEntry* ta     = &tbl[a * NPIX];
        const float*  r1base = img1 + sub_y * 64 + sub_x;
        const int     rowbase = (y_lo + by) * WSTRIDE + x_lo;

        for (int p = 0; p < NPIX; ++p) {
            TEntry e = ta[p];                               // ds_read_b128
            float2 wx = __half22float2(*(const __half2*)&e.wx);
            float2 wy = __half22float2(*(const __half2*)&e.wy);
            float  mn = e.mn;
            const int xv = e.xy & 255, yv = (e.xy >> 8) & 255;
            const float* base = &win[rowbase + yv * WSTRIDE + xv];

            float vT[10], vB[10];
            #pragma unroll
            for (int jj = 0; jj < 10; ++jj) {               // adjacent pairs -> ds_read2_b32
                vT[jj] = base[jj];
                vB[jj] = base[WSTRIDE + jj];
            }
            float r1 = r1base[((p >> 4) << 6) + (p & 15)];  // L1-resident

            #pragma unroll
            for (int j = 0; j < 9; ++j) {
                float ht = fmaf(wx.y, vT[j + 1], wx.x * vT[j]);
                float hb = fmaf(wx.y, vB[j + 1], wx.x * vB[j]);
                float rb = fmaf(wy.y, hb, wy.x * ht);
                float d  = r1 - rb;
                acc[j] = fmaf(mn, d * d, acc[j]);
            }
        }

        float best = __uint_as_float(FLTMAX_BITS);
        #pragma unroll
        for (int j = 0; j < 9; ++j) {
            bool ok = by_valid && (j <= nvx);
            float v = ok ? acc[j] : __uint_as_float(FLTMAX_BITS);
            best = fminf(best, v);
        }
        // scores are >= 0, so uint order == float order
        atomicMin(&submin[sub], __float_as_uint(best));
    }
    __syncthreads();

    if (tid == 0) {
        float t = 0.0f;
        #pragma unroll
        for (int s = 0; s < 16; ++s) t += __uint_as_float(submin[s]);
        out[b] = t;
    }
}

extern "C" void kernel_launch(void* const* d_in, const int* in_sizes, int n_in,
                              void* d_out, int out_size, void* d_ws, size_t ws_size,
                              hipStream_t stream)
{
    const float* fm1 = (const float*)d_in[0];
    const float* fm2 = (const float*)d_in[1];
    float* out = (float*)d_out;
    TEntry* tbl = (TEntry*)d_ws;   // 36,864 B of scratch

    const int nb = in_sizes[0] >> 12;   // 1024 images of 64*64

    hipLaunchKernelGGL(build_table, dim3(1), dim3(256), 0, stream, tbl);
    hipLaunchKernelGGL(randip_main, dim3(nb), dim3(256), 0, stream, fm1, fm2, tbl, out);
}

// Round 2
// 951.656 us; speedup vs baseline: 1.6107x; 1.6107x over previous
//
#include <hip/hip_runtime.h>
#include <hip/hip_fp16.h>
#include <math.h>

#define NANG 9
#define SS 16
#define NPIX 256
#define WS 71            // win row stride in floats; ODD -> by-steps spread over all 32 banks
#define NROW 70
#define NPAIR 112        // valid (sub, by) pairs
#define NITEM (NANG * NPAIR)
#define FLTMAX_BITS 0x7F7FFFFFu
#define TBL_BYTES (NANG * NPIX * 12)

// 12B per (angle,pixel):
//  wx  = half2 (ewx0, ewx1)            -- x-weights, block-validity folded in
//  wy  = half2 (s*ewy0, s*ewy1)        -- y-weights pre-scaled by s = sqrt(m/msum)
//  sxy = half(s) | (x0+1)<<16 | (y0+1)<<24
struct __align__(4) TEnt { unsigned wx, wy, sxy; };

__global__ __launch_bounds__(256) void build_table(TEnt* __restrict__ tbl,
                                                   unsigned char* __restrict__ pairs)
{
    __shared__ float red[256];
    const int p  = threadIdx.x;
    const int px = p & 15, py = p >> 4;
    for (int a = 0; a < NANG; ++a) {
        double t  = (double)(a - 4) * 0.017453292519943295; // deg2rad
        double ca = cos(t), sa = sin(t);
        float sx = (float)(ca * px - sa * py + (1.0 - ca) * 8.0 + sa * 8.0);
        float sy = (float)(sa * px + ca * py - sa * 8.0 + (1.0 - ca) * 8.0);
        float x0f = floorf(sx), y0f = floorf(sy);
        int   x0  = (int)x0f,   y0  = (int)y0f;
        float wx1 = sx - x0f, wx0 = 1.0f - wx1;
        float wy1 = sy - y0f, wy0 = 1.0f - wy1;
        float ewx0 = (x0 >= 0 && x0 < SS)         ? wx0 : 0.0f;
        float ewx1 = (x0 + 1 >= 0 && x0 + 1 < SS) ? wx1 : 0.0f;
        float ewy0 = (y0 >= 0 && y0 < SS)         ? wy0 : 0.0f;
        float ewy1 = (y0 + 1 >= 0 && y0 + 1 < SS) ? wy1 : 0.0f;
        float m = (ewx0 + ewx1) * (ewy0 + ewy1);

        red[p] = m;
        __syncthreads();
        for (int s = 128; s > 0; s >>= 1) {
            if (p < s) red[p] += red[p + s];
            __syncthreads();
        }
        float msum = red[0];
        __syncthreads();

        float sc = sqrtf(m / msum);
        x0 = max(-1, min(15, x0));   // LDS bounds safety (weights already encode validity)
        y0 = max(-1, min(15, y0));
        TEnt e;
        e.wx = (unsigned)__half_as_ushort(__float2half(ewx0)) |
               ((unsigned)__half_as_ushort(__float2half(ewx1)) << 16);
        e.wy = (unsigned)__half_as_ushort(__float2half(sc * ewy0)) |
               ((unsigned)__half_as_ushort(__float2half(sc * ewy1)) << 16);
        e.sxy = (unsigned)__half_as_ushort(__float2half(sc)) |
                ((unsigned)(x0 + 1) << 16) | ((unsigned)(y0 + 1) << 24);
        tbl[a * NPIX + p] = e;
    }
    if (p == 0) {
        int q = 0;
        for (int sub = 0; sub < 16; ++sub) {
            int sub_y = (sub >> 2) << 4;
            int y_lo = max(sub_y - 4, 0), y_hi = min(sub_y + 4, 48);
            for (int by = 0; by <= y_hi - y_lo; ++by)
                pairs[q++] = (unsigned char)(sub | (by << 4));
        }
    }
}

// One block per batch image. Work item = (angle, valid (sub,by) pair); each
// lane keeps 9 bx-shift accumulators so one 2x10 LDS row read serves 9
// candidates. Column-interp-first: u_j shared by adjacent shifts.
__global__ __launch_bounds__(256) void randip_main(const float* __restrict__ fm1,
                                                   const float* __restrict__ fm2,
                                                   const unsigned* __restrict__ gtbl,
                                                   float* __restrict__ out)
{
    __shared__ float win[NROW * WS];                    // 19880 B, zero-padded window
    __shared__ __align__(16) TEnt tbl[NANG * NPIX];     // 27648 B
    __shared__ unsigned char pairs[NPAIR];
    __shared__ unsigned submin[16];

    const int b   = blockIdx.x;
    const int tid = threadIdx.x;

    for (int i = tid; i < NROW * WS; i += 256) win[i] = 0.0f;
    {
        const uint4* src = (const uint4*)gtbl;
        uint4*       dst = (uint4*)tbl;
        for (int i = tid; i < TBL_BYTES / 16; i += 256) dst[i] = src[i];
    }
    if (tid < NPAIR) pairs[tid] = ((const unsigned char*)gtbl)[TBL_BYTES + tid];
    if (tid < 16) submin[tid] = FLTMAX_BITS;
    __syncthreads();

    const float* img2 = fm2 + (size_t)b * 4096;
    for (int i = tid; i < 4096; i += 256) {
        int y = i >> 6, x = i & 63;
        win[(y + 1) * WS + (x + 1)] = img2[i];
    }
    __syncthreads();

    const float* img1 = fm1 + (size_t)b * 4096;

    for (int item = tid; item < NITEM; item += 256) {
        const int a  = item / NPAIR;
        const int q  = item - a * NPAIR;
        const int pr = pairs[q];
        const int sub = pr & 15, by = pr >> 4;
        const int sub_x = (sub & 3) << 4;
        const int sub_y = (sub >> 2) << 4;
        const int x_lo = max(sub_x - 4, 0);
        const int x_hi = min(sub_x + 4, 48);
        const int y_lo = max(sub_y - 4, 0);
        const int nvx  = x_hi - x_lo;          // valid bx: 0..nvx

        float acc[9];
        #pragma unroll
        for (int j = 0; j < 9; ++j) acc[j] = 0.0f;

        const TEnt*  ta      = &tbl[a * NPIX];
        const float* r1base  = img1 + sub_y * 64 + sub_x;
        const int    rowbase = (y_lo + by) * WS + x_lo;

        for (int p = 0; p < NPIX; ++p) {
            TEnt e = ta[p];                                  // broadcast LDS read
            float2 wx = __half22float2(*(const __half2*)&e.wx);
            float2 wy = __half22float2(*(const __half2*)&e.wy);
            float  s  = __half2float(__ushort_as_half((unsigned short)(e.sxy & 0xffffu)));
            const int xv = (e.sxy >> 16) & 255;
            const int yv = e.sxy >> 24;
            const float* base = &win[rowbase + yv * WS + xv];

            float u[10];
            #pragma unroll
            for (int jj = 0; jj < 10; ++jj)                  // ds_read2_b32 pairs
                u[jj] = fmaf(wy.y, base[WS + jj], wy.x * base[jj]);

            float r1p = s * r1base[((p >> 4) << 6) + (p & 15)];  // L1-resident

            #pragma unroll
            for (int j = 0; j < 9; ++j) {
                float tj = fmaf(-wx.x, u[j],     r1p);
                float ej = fmaf(-wx.y, u[j + 1], tj);
                acc[j] = fmaf(ej, ej, acc[j]);
            }
        }

        float best = __uint_as_float(FLTMAX_BITS);
        #pragma unroll
        for (int j = 0; j < 9; ++j) {
            float v = (j <= nvx) ? acc[j] : __uint_as_float(FLTMAX_BITS);
            best = fminf(best, v);
        }
        // scores >= 0, so uint order == float order
        atomicMin(&submin[sub], __float_as_uint(best));
    }
    __syncthreads();

    if (tid == 0) {
        float t = 0.0f;
        #pragma unroll
        for (int s = 0; s < 16; ++s) t += __uint_as_float(submin[s]);
        out[b] = t;
    }
}

extern "C" void kernel_launch(void* const* d_in, const int* in_sizes, int n_in,
                              void* d_out, int out_size, void* d_ws, size_t ws_size,
                              hipStream_t stream)
{
    const float* fm1 = (const float*)d_in[0];
    const float* fm2 = (const float*)d_in[1];
    float* out = (float*)d_out;
    TEnt* tbl = (TEnt*)d_ws;                                    // 27,648 B
    unsigned char* pairs = (unsigned char*)d_ws + TBL_BYTES;    // + 112 B

    const int nb = in_sizes[0] >> 12;   // 1024 images of 64*64

    hipLaunchKernelGGL(build_table, dim3(1), dim3(256), 0, stream, tbl, pairs);
    hipLaunchKernelGGL(randip_main, dim3(nb), dim3(256), 0, stream,
                       fm1, fm2, (const unsigned*)d_ws, out);
}

// Round 3
// 759.894 us; speedup vs baseline: 2.0172x; 1.2524x over previous
//
#include <hip/hip_runtime.h>
#include <hip/hip_fp16.h>
#include <math.h>

#define NANG 9
#define SS 16
#define NPIX 256
#define WS 71                  // win row stride (dwords)
#define NROW 70
#define WINSZ (NROW * WS)      // 4970 dwords = 19880 B
#define NPAIR 112              // valid (sub, by) pairs
#define NITEM (NANG * NPAIR)   // 1008 items per image
#define ITEMS_PER_WAVE (NITEM / 4)
#define FLTMAX_BITS 0x7F7FFFFFu
#define TBL_BYTES (NANG * NPIX * 16)

// 16B per (angle,pixel), held in VGPRs during the main loop:
//  .x = half2 (ewx0, ewx1)         x-weights, block-validity folded in
//  .y = half2 (s*ewy0, s*ewy1)     y-weights pre-scaled by s = sqrt(m/msum)
//  .z = f32 s
//  .w = (y0+1)*WS + (x0+1)         tap offset within window

__global__ __launch_bounds__(256) void build_table(uint4* __restrict__ tbl,
                                                   unsigned char* __restrict__ pairs)
{
    __shared__ float red[256];
    const int p  = threadIdx.x;
    const int px = p & 15, py = p >> 4;
    for (int a = 0; a < NANG; ++a) {
        double t  = (double)(a - 4) * 0.017453292519943295; // deg2rad
        double ca = cos(t), sa = sin(t);
        float sx = (float)(ca * px - sa * py + (1.0 - ca) * 8.0 + sa * 8.0);
        float sy = (float)(sa * px + ca * py - sa * 8.0 + (1.0 - ca) * 8.0);
        float x0f = floorf(sx), y0f = floorf(sy);
        int   x0  = (int)x0f,   y0  = (int)y0f;
        float wx1 = sx - x0f, wx0 = 1.0f - wx1;
        float wy1 = sy - y0f, wy0 = 1.0f - wy1;
        float ewx0 = (x0 >= 0 && x0 < SS)         ? wx0 : 0.0f;
        float ewx1 = (x0 + 1 >= 0 && x0 + 1 < SS) ? wx1 : 0.0f;
        float ewy0 = (y0 >= 0 && y0 < SS)         ? wy0 : 0.0f;
        float ewy1 = (y0 + 1 >= 0 && y0 + 1 < SS) ? wy1 : 0.0f;
        float m = (ewx0 + ewx1) * (ewy0 + ewy1);

        red[p] = m;
        __syncthreads();
        for (int s = 128; s > 0; s >>= 1) {
            if (p < s) red[p] += red[p + s];
            __syncthreads();
        }
        float msum = red[0];
        __syncthreads();

        float sc = sqrtf(m / msum);
        x0 = max(-1, min(15, x0));   // LDS bounds safety (weights encode validity)
        y0 = max(-1, min(15, y0));
        uint4 e;
        e.x = (unsigned)__half_as_ushort(__float2half(ewx0)) |
              ((unsigned)__half_as_ushort(__float2half(ewx1)) << 16);
        e.y = (unsigned)__half_as_ushort(__float2half(sc * ewy0)) |
              ((unsigned)__half_as_ushort(__float2half(sc * ewy1)) << 16);
        e.z = __float_as_uint(sc);
        e.w = (unsigned)((y0 + 1) * WS + (x0 + 1));
        tbl[a * NPIX + p] = e;
    }
    if (p == 0) {
        int q = 0;
        for (int sub = 0; sub < 16; ++sub) {
            int sub_y = (sub >> 2) << 4;
            int y_lo = max(sub_y - 4, 0), y_hi = min(sub_y + 4, 48);
            for (int by = 0; by <= y_hi - y_lo; ++by)
                pairs[q++] = (unsigned char)(sub | (by << 4));
        }
    }
}

// butterfly-sum across 64 lanes on the VALU pipe (no LDS traffic); total in lane 63
#define DPPADD(v, ctrl, rmask)                                                   \
    v += __int_as_float(__builtin_amdgcn_update_dpp(                             \
            0, __float_as_int(v), ctrl, rmask, 0xf, true))

#define PIX(te, r1v)                                                             \
    {                                                                            \
        float2 wx = __half22float2(*(const __half2*)&te.x);                      \
        float2 wy = __half22float2(*(const __half2*)&te.y);                      \
        float  s  = __uint_as_float(te.z);                                       \
        const float* base = &win[rowbase + (int)te.w];                           \
        float u[10];                                                             \
        _Pragma("unroll")                                                        \
        for (int jj = 0; jj < 10; ++jj)                                          \
            u[jj] = fmaf(wy.y, base[WS + jj], wy.x * base[jj]);                  \
        float r1s = s * (r1v);                                                   \
        _Pragma("unroll")                                                        \
        for (int j = 0; j < 9; ++j) {                                            \
            float tj = fmaf(-wx.x, u[j],     r1s);                               \
            float ej = fmaf(-wx.y, u[j + 1], tj);                                \
            acc[j] = fmaf(ej, ej, acc[j]);                                       \
        }                                                                        \
    }

// One block per image, 4 waves. Each wave owns a contiguous range of items
// (a, sub, by); its 64 lanes split the 256 pixels (4 each). Window reads are
// wave-uniform-base + per-pixel offset -> ~2-3-way banks by construction.
__global__ __launch_bounds__(256) void randip_main(const float* __restrict__ fm1,
                                                   const float* __restrict__ fm2,
                                                   const uint4* __restrict__ gt,
                                                   const unsigned char* __restrict__ gpairs,
                                                   float* __restrict__ out)
{
    __shared__ float win[WINSZ];           // 19880 B zero-padded window
    __shared__ unsigned char pairs_s[NPAIR];
    __shared__ unsigned submin[16];

    const int b    = blockIdx.x;
    const int tid  = threadIdx.x;
    const int wave = tid >> 6;
    const int lane = tid & 63;

    for (int i = tid; i < WINSZ; i += 256) win[i] = 0.0f;
    if (tid < NPAIR) pairs_s[tid] = gpairs[tid];
    if (tid < 16) submin[tid] = FLTMAX_BITS;
    __syncthreads();

    const float* img2 = fm2 + (size_t)b * 4096;
    for (int i = tid; i < 4096; i += 256) {
        int y = i >> 6, x = i & 63;
        win[(y + 1) * WS + (x + 1)] = img2[i];
    }
    __syncthreads();

    const float* img1 = fm1 + (size_t)b * 4096;

    // wave w: items [w*252, (w+1)*252); track (a, q) incrementally
    int a = (wave * ITEMS_PER_WAVE) / NPAIR;
    int q = (wave * ITEMS_PER_WAVE) - a * NPAIR;

    uint4 te0, te1, te2, te3;
    {
        const uint4* tp = gt + a * NPIX;
        te0 = tp[lane]; te1 = tp[64 + lane]; te2 = tp[128 + lane]; te3 = tp[192 + lane];
    }
    int sub_cur = -1, nvx = 0, x_lo = 0, y_lo = 0;
    float r1v0 = 0.f, r1v1 = 0.f, r1v2 = 0.f, r1v3 = 0.f;

    for (int k = 0; k < ITEMS_PER_WAVE; ++k) {
        const int pr  = pairs_s[q];
        const int sub = pr & 15, by = pr >> 4;
        if (sub != sub_cur) {
            sub_cur = sub;
            const int sub_x = (sub & 3) << 4;
            const int sub_y = (sub >> 2) << 4;
            x_lo = max(sub_x - 4, 0);
            y_lo = max(sub_y - 4, 0);
            nvx  = min(sub_x + 4, 48) - x_lo;
            const float* r1p = img1 + (sub_y + (lane >> 4)) * 64 + sub_x + (lane & 15);
            r1v0 = r1p[0];
            r1v1 = r1p[4 * 64];
            r1v2 = r1p[8 * 64];
            r1v3 = r1p[12 * 64];
        }
        const int rowbase = (y_lo + by) * WS + x_lo;

        float acc[9];
        #pragma unroll
        for (int j = 0; j < 9; ++j) acc[j] = 0.0f;

        PIX(te0, r1v0)
        PIX(te1, r1v1)
        PIX(te2, r1v2)
        PIX(te3, r1v3)

        #pragma unroll
        for (int j = 0; j < 9; ++j) {
            float v = acc[j];
            DPPADD(v, 0xB1,  0xf);   // quad_perm [1,0,3,2]  (xor 1)
            DPPADD(v, 0x4E,  0xf);   // quad_perm [2,3,0,1]  (xor 2)
            DPPADD(v, 0x141, 0xf);   // row_half_mirror      (xor 4)
            DPPADD(v, 0x140, 0xf);   // row_mirror           (xor 8)
            DPPADD(v, 0x142, 0xa);   // row_bcast:15 -> rows 1,3
            DPPADD(v, 0x143, 0xc);   // row_bcast:31 -> rows 2,3
            acc[j] = v;              // lane 63 holds the full sum
        }
        if (lane == 63) {
            float best = __uint_as_float(FLTMAX_BITS);
            #pragma unroll
            for (int j = 0; j < 9; ++j) {
                float v = (j <= nvx) ? acc[j] : __uint_as_float(FLTMAX_BITS);
                best = fminf(best, v);
            }
            atomicMin(&submin[sub], __float_as_uint(best)); // scores >= 0
        }

        if (++q == NPAIR) {          // next angle: reload table registers
            q = 0; ++a;
            if (k + 1 < ITEMS_PER_WAVE) {
                const uint4* tp = gt + a * NPIX;
                te0 = tp[lane]; te1 = tp[64 + lane];
                te2 = tp[128 + lane]; te3 = tp[192 + lane];
            }
        }
    }
    __syncthreads();

    if (tid == 0) {
        float t = 0.0f;
        #pragma unroll
        for (int s = 0; s < 16; ++s) t += __uint_as_float(submin[s]);
        out[b] = t;
    }
}

extern "C" void kernel_launch(void* const* d_in, const int* in_sizes, int n_in,
                              void* d_out, int out_size, void* d_ws, size_t ws_size,
                              hipStream_t stream)
{
    const float* fm1 = (const float*)d_in[0];
    const float* fm2 = (const float*)d_in[1];
    float* out = (float*)d_out;
    uint4* tbl = (uint4*)d_ws;                                  // 36,864 B
    unsigned char* pairs = (unsigned char*)d_ws + TBL_BYTES;    // + 112 B

    const int nb = in_sizes[0] >> 12;   // 1024 images of 64*64

    hipLaunchKernelGGL(build_table, dim3(1), dim3(256), 0, stream, tbl, pairs);
    hipLaunchKernelGGL(randip_main, dim3(nb), dim3(256), 0, stream,
                       fm1, fm2, tbl, pairs, out);
}

// Round 4
// 501.392 us; speedup vs baseline: 3.0572x; 1.5156x over previous
//
#include <hip/hip_runtime.h>
#include <hip/hip_fp16.h>
#include <math.h>

#define NANG 9
#define SS 16
#define NPIX 256
#define WS 72                  // win row stride (dwords); lanes tile banks exactly 2-way
#define NROW 70
#define WINSZ (NROW * WS)      // 5040 dwords = 20160 B
#define NITEM (NANG * 16)      // 144 (angle, sub) items per image
#define IPW (NITEM / 4)        // 36 per wave
#define FLTMAX_BITS 0x7F7FFFFFu

// 16B per (angle,pixel):
//  .x = half2 (ewx0, ewx1)         x-weights, block-validity folded in
//  .y = half2 (s*ewy0, s*ewy1)     y-weights pre-scaled by s = sqrt(m/msum)
//  .z = f32 s
//  .w = (y0+1)*WS + (x0+1)         tap offset within padded window

__global__ __launch_bounds__(256) void build_table(uint4* __restrict__ tbl)
{
    __shared__ float red[256];
    const int p  = threadIdx.x;
    const int px = p & 15, py = p >> 4;
    for (int a = 0; a < NANG; ++a) {
        double t  = (double)(a - 4) * 0.017453292519943295; // deg2rad
        double ca = cos(t), sa = sin(t);
        float sx = (float)(ca * px - sa * py + (1.0 - ca) * 8.0 + sa * 8.0);
        float sy = (float)(sa * px + ca * py - sa * 8.0 + (1.0 - ca) * 8.0);
        float x0f = floorf(sx), y0f = floorf(sy);
        int   x0  = (int)x0f,   y0  = (int)y0f;
        float wx1 = sx - x0f, wx0 = 1.0f - wx1;
        float wy1 = sy - y0f, wy0 = 1.0f - wy1;
        float ewx0 = (x0 >= 0 && x0 < SS)         ? wx0 : 0.0f;
        float ewx1 = (x0 + 1 >= 0 && x0 + 1 < SS) ? wx1 : 0.0f;
        float ewy0 = (y0 >= 0 && y0 < SS)         ? wy0 : 0.0f;
        float ewy1 = (y0 + 1 >= 0 && y0 + 1 < SS) ? wy1 : 0.0f;
        float m = (ewx0 + ewx1) * (ewy0 + ewy1);

        red[p] = m;
        __syncthreads();
        for (int s = 128; s > 0; s >>= 1) {
            if (p < s) red[p] += red[p + s];
            __syncthreads();
        }
        float msum = red[0];
        __syncthreads();

        float sc = sqrtf(m / msum);
        x0 = max(-1, min(15, x0));   // LDS bounds safety (weights encode validity)
        y0 = max(-1, min(15, y0));
        uint4 e;
        e.x = (unsigned)__half_as_ushort(__float2half(ewx0)) |
              ((unsigned)__half_as_ushort(__float2half(ewx1)) << 16);
        e.y = (unsigned)__half_as_ushort(__float2half(sc * ewy0)) |
              ((unsigned)__half_as_ushort(__float2half(sc * ewy1)) << 16);
        e.z = __float_as_uint(sc);
        e.w = (unsigned)((y0 + 1) * WS + (x0 + 1));
        tbl[a * NPIX + p] = e;
    }
}

// butterfly-sum across 64 lanes on the VALU pipe; full sum lands in lane 63
#define DPPADD(v, ctrl, rmask)                                                   \
    v += __int_as_float(__builtin_amdgcn_update_dpp(                             \
            0, __float_as_int(v), ctrl, rmask, 0xf, true))

// Load one raw window row per pixel-set and x-interp it into h[k][0..8].
__device__ __forceinline__ void rowload(const float* __restrict__ win,
                                        int (&addr)[4],
                                        const float (&wx0)[4], const float (&wx1)[4],
                                        float (&h)[4][9])
{
    #pragma unroll
    for (int k = 0; k < 4; ++k) {
        float raw[10];
        #pragma unroll
        for (int j = 0; j < 10; ++j) raw[j] = win[addr[k] + j];   // 5x ds_read2_b32
        #pragma unroll
        for (int c = 0; c < 9; ++c)
            h[k][c] = fmaf(wx1[k], raw[c + 1], wx0[k] * raw[c]);
        addr[k] += WS;
    }
}

// One by-step: y-interp (hp,hc) for all 4 pixel-sets x 9 bx, square-accumulate,
// DPP-reduce over lanes, min over valid bx, atomicMin into submin[sub].
__device__ __forceinline__ void bystep(const float (&hp)[4][9], const float (&hc)[4][9],
                                       const float (&wys0)[4], const float (&wys1)[4],
                                       const float (&r1s)[4], int nvx,
                                       unsigned* __restrict__ sm, int lane)
{
    float acc[9];
    #pragma unroll
    for (int j = 0; j < 9; ++j) acc[j] = 0.0f;
    #pragma unroll
    for (int k = 0; k < 4; ++k) {
        #pragma unroll
        for (int j = 0; j < 9; ++j) {
            float e = fmaf(-wys0[k], hp[k][j], r1s[k]);
            e = fmaf(-wys1[k], hc[k][j], e);
            acc[j] = fmaf(e, e, acc[j]);
        }
    }
    #pragma unroll
    for (int j = 0; j < 9; ++j) {
        float v = acc[j];
        DPPADD(v, 0xB1,  0xf);   // xor 1
        DPPADD(v, 0x4E,  0xf);   // xor 2
        DPPADD(v, 0x141, 0xf);   // row_half_mirror (xor 4)
        DPPADD(v, 0x140, 0xf);   // row_mirror      (xor 8)
        DPPADD(v, 0x142, 0xa);   // row_bcast:15 -> rows 1,3
        DPPADD(v, 0x143, 0xc);   // row_bcast:31 -> rows 2,3
        acc[j] = v;
    }
    if (lane == 63) {
        float best = __uint_as_float(FLTMAX_BITS);
        #pragma unroll
        for (int j = 0; j < 9; ++j) {
            float v = (j <= nvx) ? acc[j] : __uint_as_float(FLTMAX_BITS);
            best = fminf(best, v);
        }
        atomicMin(sm, __float_as_uint(best));   // scores >= 0: uint order == float order
    }
}

template<int NBY>
__device__ __forceinline__ void proc(const float* __restrict__ win, int (&addr)[4],
                                     const float (&wx0)[4], const float (&wx1)[4],
                                     const float (&wys0)[4], const float (&wys1)[4],
                                     const float (&r1s)[4], int nvx,
                                     unsigned* __restrict__ sm, int lane)
{
    float hA[4][9], hB[4][9];
    rowload(win, addr, wx0, wx1, hA);
    #pragma unroll
    for (int by = 0; by < NBY + 1; by += 2) {
        rowload(win, addr, wx0, wx1, hB);
        bystep(hA, hB, wys0, wys1, r1s, nvx, sm, lane);
        if (by + 1 < NBY + 1) {
            rowload(win, addr, wx0, wx1, hA);
            bystep(hB, hA, wys0, wys1, r1s, nvx, sm, lane);
        }
    }
}

// One block per image, 4 waves. Item = (angle, sub); wave streams window rows,
// x-interps once per row into registers, y-interp serves two by's per row.
__global__ __launch_bounds__(256) void randip_main(const float* __restrict__ fm1,
                                                   const float* __restrict__ fm2,
                                                   const uint4* __restrict__ gt,
                                                   float* __restrict__ out)
{
    __shared__ float win[WINSZ];
    __shared__ unsigned submin[16];

    const int b    = blockIdx.x;
    const int tid  = threadIdx.x;
    const int wave = tid >> 6;
    const int lane = tid & 63;

    for (int i = tid; i < WINSZ; i += 256) win[i] = 0.0f;
    if (tid < 16) submin[tid] = FLTMAX_BITS;
    __syncthreads();

    const float* img2 = fm2 + (size_t)b * 4096;
    for (int i = tid; i < 4096; i += 256) {
        int y = i >> 6, x = i & 63;
        win[(y + 1) * WS + (x + 1)] = img2[i];
    }
    __syncthreads();

    const float* img1 = fm1 + (size_t)b * 4096;

    int a_cur = -1;
    float wx0[4], wx1[4], wys0[4], wys1[4], sca[4];
    int   off[4];

    for (int i = wave * IPW; i < (wave + 1) * IPW; ++i) {
        const int a = i >> 4, sub = i & 15;
        if (a != a_cur) {                     // <=3 reloads per wave, coalesced b128
            a_cur = a;
            const uint4* tp = gt + a * NPIX + lane;
            #pragma unroll
            for (int k = 0; k < 4; ++k) {
                uint4 te = tp[64 * k];
                float2 x2 = __half22float2(*(const __half2*)&te.x);
                float2 y2 = __half22float2(*(const __half2*)&te.y);
                wx0[k] = x2.x; wx1[k] = x2.y;
                wys0[k] = y2.x; wys1[k] = y2.y;
                sca[k] = __uint_as_float(te.z);
                off[k] = (int)te.w;
            }
        }
        const int sub_x = (sub & 3) << 4;
        const int sub_y = (sub >> 2) << 4;
        const int x_lo = max(sub_x - 4, 0);
        const int y_lo = max(sub_y - 4, 0);
        const int nvx = min(sub_x + 4, 48) - x_lo;   // 4 or 8
        const int nby = min(sub_y + 4, 48) - y_lo;   // 4 or 8
        const int rowbase0 = y_lo * WS + x_lo;

        float r1s[4];
        const float* r1p = img1 + (sub_y + (lane >> 4)) * 64 + sub_x + (lane & 15);
        #pragma unroll
        for (int k = 0; k < 4; ++k) r1s[k] = sca[k] * r1p[k * 4 * 64];

        int addr[4];
        #pragma unroll
        for (int k = 0; k < 4; ++k) addr[k] = rowbase0 + off[k];

        if (nby == 8) proc<8>(win, addr, wx0, wx1, wys0, wys1, r1s, nvx, &submin[sub], lane);
        else          proc<4>(win, addr, wx0, wx1, wys0, wys1, r1s, nvx, &submin[sub], lane);
    }
    __syncthreads();

    if (tid == 0) {
        float t = 0.0f;
        #pragma unroll
        for (int s = 0; s < 16; ++s) t += __uint_as_float(submin[s]);
        out[b] = t;
    }
}

extern "C" void kernel_launch(void* const* d_in, const int* in_sizes, int n_in,
                              void* d_out, int out_size, void* d_ws, size_t ws_size,
                              hipStream_t stream)
{
    const float* fm1 = (const float*)d_in[0];
    const float* fm2 = (const float*)d_in[1];
    float* out = (float*)d_out;
    uint4* tbl = (uint4*)d_ws;   // 36,864 B scratch

    const int nb = in_sizes[0] >> 12;   // 1024 images of 64*64

    hipLaunchKernelGGL(build_table, dim3(1), dim3(256), 0, stream, tbl);
    hipLaunchKernelGGL(randip_main, dim3(nb), dim3(256), 0, stream, fm1, fm2, tbl, out);
}

// Round 5
// 367.465 us; speedup vs baseline: 4.1714x; 1.3645x over previous
//
#include <hip/hip_runtime.h>
#include <hip/hip_fp16.h>
#include <math.h>

#define NANG 9
#define SS 16
#define NPIX 256
#define WSH 72                 // window row stride in half2 pairs; lanes tile banks 2-way
#define NROWW 70
#define WINSZH (NROWW * WSH)   // 5040 pair-dwords = 20160 B
#define NITEM (NANG * 16)      // 144 (angle, sub) items per image
#define IPW (NITEM / 4)        // 36 per wave
#define FLTMAX_BITS 0x7F7FFFFFu

// 16B per (angle,pixel):
//  .x = half2 (ewx0, ewx1)           x-weights, block-validity folded in
//  .y = half2 (-s*ewy0, -s*ewy1)     NEGATED y-weights pre-scaled by s = sqrt(m/msum)
//  .z = f32 s
//  .w = (y0+1)*WSH + (x0+1)          tap offset within padded pair-window

__global__ __launch_bounds__(256) void build_table(uint4* __restrict__ tbl)
{
    __shared__ float red[256];
    const int p  = threadIdx.x;
    const int px = p & 15, py = p >> 4;
    for (int a = 0; a < NANG; ++a) {
        double t  = (double)(a - 4) * 0.017453292519943295; // deg2rad
        double ca = cos(t), sa = sin(t);
        float sx = (float)(ca * px - sa * py + (1.0 - ca) * 8.0 + sa * 8.0);
        float sy = (float)(sa * px + ca * py - sa * 8.0 + (1.0 - ca) * 8.0);
        float x0f = floorf(sx), y0f = floorf(sy);
        int   x0  = (int)x0f,   y0  = (int)y0f;
        float wx1 = sx - x0f, wx0 = 1.0f - wx1;
        float wy1 = sy - y0f, wy0 = 1.0f - wy1;
        float ewx0 = (x0 >= 0 && x0 < SS)         ? wx0 : 0.0f;
        float ewx1 = (x0 + 1 >= 0 && x0 + 1 < SS) ? wx1 : 0.0f;
        float ewy0 = (y0 >= 0 && y0 < SS)         ? wy0 : 0.0f;
        float ewy1 = (y0 + 1 >= 0 && y0 + 1 < SS) ? wy1 : 0.0f;
        float m = (ewx0 + ewx1) * (ewy0 + ewy1);

        red[p] = m;
        __syncthreads();
        for (int s = 128; s > 0; s >>= 1) {
            if (p < s) red[p] += red[p + s];
            __syncthreads();
        }
        float msum = red[0];
        __syncthreads();

        float sc = sqrtf(m / msum);
        x0 = max(-1, min(15, x0));   // LDS bounds safety (weights encode validity)
        y0 = max(-1, min(15, y0));
        uint4 e;
        e.x = (unsigned)__half_as_ushort(__float2half(ewx0)) |
              ((unsigned)__half_as_ushort(__float2half(ewx1)) << 16);
        e.y = (unsigned)__half_as_ushort(__float2half(-sc * ewy0)) |
              ((unsigned)__half_as_ushort(__float2half(-sc * ewy1)) << 16);
        e.z = __float_as_uint(sc);
        e.w = (unsigned)((y0 + 1) * WSH + (x0 + 1));
        tbl[a * NPIX + p] = e;
    }
}

// butterfly-sum across 64 lanes on the VALU pipe; full sum lands in lane 63
#define DPPADD(v, ctrl, rmask)                                                   \
    v += __int_as_float(__builtin_amdgcn_update_dpp(                             \
            0, __float_as_int(v), ctrl, rmask, 0xf, true))

// Load one pair-row per k and packed-x-interp into h[k][0..NP-1] (h pairs).
template<int NP>
__device__ __forceinline__ void rowload(const __half2* __restrict__ winh,
                                        int (&addr)[4],
                                        const __half2 (&wx0)[4], const __half2 (&wx1)[4],
                                        __half2 (&h)[4][NP])
{
    #pragma unroll
    for (int k = 0; k < 4; ++k) {
        __half2 d[2 * NP];
        #pragma unroll
        for (int j = 0; j < 2 * NP; ++j) d[j] = winh[addr[k] + j];  // ds_read2_b32
        #pragma unroll
        for (int c = 0; c < NP; ++c)
            h[k][c] = __hfma2(wx1[k], d[2 * c + 1], __hmul2(wx0[k], d[2 * c]));
        addr[k] += WSH;
    }
}

// One by-step: packed y-interp + square-acc (2 bx per op), unpack, DPP-reduce,
// min over the (compile-time) valid bx count, atomicMin into submin[sub].
template<int NP>
__device__ __forceinline__ void bystep(const __half2 (&hp)[4][NP], const __half2 (&hc)[4][NP],
                                       const __half2 (&wy0n)[4], const __half2 (&wy1n)[4],
                                       const __half2 (&r1s)[4],
                                       unsigned* __restrict__ sm, int lane)
{
    __half2 acc[NP];
    #pragma unroll
    for (int c = 0; c < NP; ++c) acc[c] = __floats2half2_rn(0.f, 0.f);
    #pragma unroll
    for (int k = 0; k < 4; ++k) {
        #pragma unroll
        for (int c = 0; c < NP; ++c) {
            __half2 e = __hfma2(wy0n[k], hp[k][c], r1s[k]);  // r1s - wys0*hp
            e = __hfma2(wy1n[k], hc[k][c], e);               //     - wys1*hc
            acc[c] = __hfma2(e, e, acc[c]);
        }
    }
    constexpr int NJ = 2 * NP - 1;     // valid bx count: NP=5 -> 9, NP=3 -> 5
    float v[NJ];
    #pragma unroll
    for (int c = 0; c < NP; ++c) {
        v[2 * c] = __low2float(acc[c]);
        if (2 * c + 1 < NJ) v[2 * c + 1] = __high2float(acc[c]);
    }
    #pragma unroll
    for (int j = 0; j < NJ; ++j) {
        DPPADD(v[j], 0xB1,  0xf);   // xor 1
        DPPADD(v[j], 0x4E,  0xf);   // xor 2
        DPPADD(v[j], 0x141, 0xf);   // row_half_mirror (xor 4)
        DPPADD(v[j], 0x140, 0xf);   // row_mirror      (xor 8)
        DPPADD(v[j], 0x142, 0xa);   // row_bcast:15 -> rows 1,3
        DPPADD(v[j], 0x143, 0xc);   // row_bcast:31 -> rows 2,3
    }
    if (lane == 63) {
        float best = v[0];
        #pragma unroll
        for (int j = 1; j < NJ; ++j) best = fminf(best, v[j]);
        atomicMin(sm, __float_as_uint(best));   // scores >= 0: uint order == float order
    }
}

template<int NBY, int NP>
__device__ __forceinline__ void proc(const __half2* __restrict__ winh, int (&addr)[4],
                                     const __half2 (&wx0)[4], const __half2 (&wx1)[4],
                                     const __half2 (&wy0n)[4], const __half2 (&wy1n)[4],
                                     const __half2 (&r1s)[4],
                                     unsigned* __restrict__ sm, int lane)
{
    __half2 hA[4][NP], hB[4][NP];
    rowload<NP>(winh, addr, wx0, wx1, hA);
    #pragma unroll
    for (int by = 0; by < NBY + 1; by += 2) {
        rowload<NP>(winh, addr, wx0, wx1, hB);
        bystep<NP>(hA, hB, wy0n, wy1n, r1s, sm, lane);
        if (by + 1 < NBY + 1) {
            rowload<NP>(winh, addr, wx0, wx1, hA);
            bystep<NP>(hB, hA, wy0n, wy1n, r1s, sm, lane);
        }
    }
}

// One block per image, 4 waves. Item = (angle, sub); wave streams window rows,
// packed-f16 x-interp once per row, y-interp serves two by's per row, two bx
// candidates per packed instruction.
__global__ __launch_bounds__(256) void randip_main(const float* __restrict__ fm1,
                                                   const float* __restrict__ fm2,
                                                   const uint4* __restrict__ gt,
                                                   float* __restrict__ out)
{
    __shared__ __half2 winh[WINSZH];    // 20160 B: pair c = (w[c], w[c+1]), f16
    __shared__ unsigned submin[16];

    const int b    = blockIdx.x;
    const int tid  = threadIdx.x;
    const int wave = tid >> 6;
    const int lane = tid & 63;

    for (int i = tid; i < WINSZH; i += 256) winh[i] = __floats2half2_rn(0.f, 0.f);
    if (tid < 16) submin[tid] = FLTMAX_BITS;
    __syncthreads();

    // fill pair-window from global: entry (r+1, c) = (w[r+1][c], w[r+1][c+1])
    const float* img2 = fm2 + (size_t)b * 4096;
    for (int i = tid; i < 64 * 65; i += 256) {
        int r = i / 65, c = i - r * 65;          // r: img2 row 0..63, c: 0..64
        float lo = (c >= 1)  ? img2[r * 64 + c - 1] : 0.f;
        float hi = (c <= 63) ? img2[r * 64 + c]     : 0.f;
        winh[(r + 1) * WSH + c] = __floats2half2_rn(lo, hi);
    }
    __syncthreads();

    const float* img1 = fm1 + (size_t)b * 4096;

    int a_cur = -1;
    __half2 wx0[4], wx1[4], wy0n[4], wy1n[4], r1s[4];
    float   sca[4];
    int     off[4];

    for (int i = wave * IPW; i < (wave + 1) * IPW; ++i) {
        const int a = i >> 4, sub = i & 15;
        if (a != a_cur) {                     // <=3 reloads per wave, coalesced b128
            a_cur = a;
            const uint4* tp = gt + a * NPIX + lane;
            #pragma unroll
            for (int k = 0; k < 4; ++k) {
                uint4 te = tp[64 * k];
                __half2 X = *(const __half2*)&te.x;
                __half2 Y = *(const __half2*)&te.y;
                wx0[k]  = __half2half2(__low2half(X));
                wx1[k]  = __half2half2(__high2half(X));
                wy0n[k] = __half2half2(__low2half(Y));
                wy1n[k] = __half2half2(__high2half(Y));
                sca[k]  = __uint_as_float(te.z);
                off[k]  = (int)te.w;
            }
        }
        const int sub_x = (sub & 3) << 4;
        const int sub_y = (sub >> 2) << 4;
        const int x_lo = max(sub_x - 4, 0);
        const int y_lo = max(sub_y - 4, 0);
        const int nvx = min(sub_x + 4, 48) - x_lo;   // 4 or 8
        const int nby = min(sub_y + 4, 48) - y_lo;   // 4 or 8
        const int rowbase0 = y_lo * WSH + x_lo;

        const float* r1p = img1 + (sub_y + (lane >> 4)) * 64 + sub_x + (lane & 15);
        #pragma unroll
        for (int k = 0; k < 4; ++k)
            r1s[k] = __float2half2_rn(sca[k] * r1p[k * 4 * 64]);

        int addr[4];
        #pragma unroll
        for (int k = 0; k < 4; ++k) addr[k] = rowbase0 + off[k];

        unsigned* sm = &submin[sub];
        if (nby == 8) {
            if (nvx == 8) proc<8, 5>(winh, addr, wx0, wx1, wy0n, wy1n, r1s, sm, lane);
            else          proc<8, 3>(winh, addr, wx0, wx1, wy0n, wy1n, r1s, sm, lane);
        } else {
            if (nvx == 8) proc<4, 5>(winh, addr, wx0, wx1, wy0n, wy1n, r1s, sm, lane);
            else          proc<4, 3>(winh, addr, wx0, wx1, wy0n, wy1n, r1s, sm, lane);
        }
    }
    __syncthreads();

    if (tid == 0) {
        float t = 0.0f;
        #pragma unroll
        for (int s = 0; s < 16; ++s) t += __uint_as_float(submin[s]);
        out[b] = t;
    }
}

extern "C" void kernel_launch(void* const* d_in, const int* in_sizes, int n_in,
                              void* d_out, int out_size, void* d_ws, size_t ws_size,
                              hipStream_t stream)
{
    const float* fm1 = (const float*)d_in[0];
    const float* fm2 = (const float*)d_in[1];
    float* out = (float*)d_out;
    uint4* tbl = (uint4*)d_ws;   // 36,864 B scratch

    const int nb = in_sizes[0] >> 12;   // 1024 images of 64*64

    hipLaunchKernelGGL(build_table, dim3(1), dim3(256), 0, stream, tbl);
    hipLaunchKernelGGL(randip_main, dim3(nb), dim3(256), 0, stream, fm1, fm2, tbl, out);
}